// Round 10
// baseline (66.573 us; speedup 1.0000x reference)
//
#include <hip/hip_runtime.h>
#include <hip/hip_bf16.h>
#include <hip/hip_fp16.h>

#define D 8192
#define NPAIR 523776.0
#define NSTEPS 16      // K-chunk 512 / BK 32

typedef short short8 __attribute__((ext_vector_type(8)));
typedef float f32x4 __attribute__((ext_vector_type(4)));

__device__ __forceinline__ short8 cvt8(const float4 a, const float4 b) {
    union { short8 s; __hip_bfloat162 h[4]; } u;
    u.h[0] = __float22bfloat162_rn(make_float2(a.x, a.y));
    u.h[1] = __float22bfloat162_rn(make_float2(a.z, a.w));
    u.h[2] = __float22bfloat162_rn(make_float2(b.x, b.y));
    u.h[3] = __float22bfloat162_rn(make_float2(b.z, b.w));
    return u.s;
}

// 640 blocks, bid = x(0..7) + 8*s, s in 0..79.
// x: m = x>>2 (matrix), xr = x&3.  s: t = s>>2 (tile 0..19), cc = s&3.
// chunk c = cc*4 + xr (16 chunks of K=512; chunk class pinned to XCD set).
// tile t -> (ti, tjc): rows ti*128..+128 (A), cols tjc*256..+256 (B);
// valid tiles: ti <= 2*tjc+1, t = tjc*(tjc+1) + ti.  Straddle tiles
// ((ti>>1)==tjc) contain the diagonal; their below-diag half is never read.
__device__ __forceinline__ void decode_bid(int bid, int& m, int& ti, int& tjc, int& c) {
    int x = bid & 7, s = bid >> 3;
    m = x >> 2;
    int t = s >> 2;
    c = ((s & 3) << 2) + (x & 3);
    if (t >= 12)      { tjc = 3; ti = t - 12; }
    else if (t >= 6)  { tjc = 2; ti = t - 6; }
    else if (t >= 2)  { tjc = 1; ti = t - 2; }
    else              { tjc = 0; ti = t; }
}
__device__ __forceinline__ int bid_from(int m, int t, int c) {
    return ((m << 2) + (c & 3)) + (((t << 2) + (c >> 2)) << 3);
}

// one pipeline step: MFMA on ls[S&1]; write staged regs (data for step S+1) to
// ls[(S&1)^1]; issue loads for step S+2.
#define GRAM_STEP(S) { \
    const int cur_ = (S) & 1; \
    const char* __restrict__ buf = (const char*)ls[cur_]; \
    __builtin_amdgcn_s_setprio(1); \
    short8 bf0 = *(const short8*)(buf + rbB + kby); \
    short8 bf1 = *(const short8*)(buf + rbB + 1024 + kby); \
    short8 bf2 = *(const short8*)(buf + rbB + 2048 + kby); \
    short8 bf3 = *(const short8*)(buf + rbB + 3072 + kby); \
    _Pragma("unroll") \
    for (int mi = 0; mi < 4; ++mi) { \
        short8 af = *(const short8*)(buf + rbA + mi * 1024 + kby); \
        acc[mi][0] = __builtin_amdgcn_mfma_f32_16x16x32_bf16(af, bf0, acc[mi][0], 0, 0, 0); \
        acc[mi][1] = __builtin_amdgcn_mfma_f32_16x16x32_bf16(af, bf1, acc[mi][1], 0, 0, 0); \
        acc[mi][2] = __builtin_amdgcn_mfma_f32_16x16x32_bf16(af, bf2, acc[mi][2], 0, 0, 0); \
        acc[mi][3] = __builtin_amdgcn_mfma_f32_16x16x32_bf16(af, bf3, acc[mi][3], 0, 0, 0); \
    } \
    __builtin_amdgcn_s_setprio(0); \
    if ((S) + 1 < NSTEPS) { \
        char* __restrict__ nb = (char*)ls[cur_ ^ 1]; \
        *(short8*)(nb + wbyA)  = cvt8(ra[0], ra[1]); \
        *(short8*)(nb + wbyB0) = cvt8(rb[0], rb[1]); \
        *(short8*)(nb + wbyB1) = cvt8(rb[2], rb[3]); \
        if ((S) + 2 < NSTEPS) { \
            const float4* pa_ = (const float4*)(gA + ((S) + 2) * 32); \
            ra[0] = pa_[0]; ra[1] = pa_[1]; \
            const float4* pb_ = (const float4*)(gB + ((S) + 2) * 32); \
            rb[0] = pb_[0]; rb[1] = pb_[1]; rb[2] = pb_[2]; rb[3] = pb_[3]; \
        } \
    } \
    asm volatile("s_waitcnt lgkmcnt(0)" ::: "memory"); \
    __builtin_amdgcn_s_barrier(); \
}

template<bool STORE>
__global__ __launch_bounds__(512, 3)
void gram_kernel(const float* __restrict__ pred, const float* __restrict__ tgt,
                 void* __restrict__ outv, float* __restrict__ norms) {
    int m, ti, tjc, c;
    decode_bid(blockIdx.x, m, ti, tjc, c);
    const float* __restrict__ x = m ? tgt : pred;
    const int k0 = c * 512;

    // LDS per buffer: A 128 rows x 64B (8 KB) | B 256 rows x 64B (16 KB)
    __shared__ short ls[2][12288];

    const int tid = threadIdx.x;
    const int lane = tid & 63;
    const int wid = tid >> 6;
    const int wr = wid >> 2, wc = wid & 3;   // 8 waves: 2x4 grid of 64x64 wave tiles

    // A staging: row = tid>>2 (0..127), slot = tid&3 (8 floats each)
    const int arow = tid >> 2, aslot = tid & 3;
    const float* __restrict__ gA = x + (size_t)(ti * 128 + arow) * D + k0 + aslot * 8;
    const int wbyA = arow * 64 + ((aslot ^ ((arow >> 1) & 3)) << 4);
    // B staging: row = tid>>1 (0..255), slots 2*(tid&1), +1 (16 consecutive floats)
    const int brow = tid >> 1, bs0 = (tid & 1) << 1;
    const float* __restrict__ gB = x + (size_t)(tjc * 256 + brow) * D + k0 + bs0 * 8;
    const int wbyB0 = 8192 + brow * 64 + (((bs0)     ^ ((brow >> 1) & 3)) << 4);
    const int wbyB1 = 8192 + brow * 64 + (((bs0 | 1) ^ ((brow >> 1) & 3)) << 4);

    // fragment read offsets (swizzle-consistent: 16-row strides don't touch (row>>1)&3)
    const int rbA = (wr * 64 + (lane & 15)) * 64;
    const int rbB = 8192 + (wc * 64 + (lane & 15)) * 64;
    const int kby = (((lane >> 4) ^ (((lane & 15) >> 1) & 3)) << 4);

    f32x4 zero = {0.f, 0.f, 0.f, 0.f};
    f32x4 acc[4][4];
#pragma unroll
    for (int mi = 0; mi < 4; ++mi)
#pragma unroll
        for (int ni = 0; ni < 4; ++ni) acc[mi][ni] = zero;

    float4 ra[2], rb[4];
    // prologue: load step0 -> write buf0 -> load step1
    { const float4* pa = (const float4*)gA; ra[0] = pa[0]; ra[1] = pa[1];
      const float4* pb = (const float4*)gB; rb[0] = pb[0]; rb[1] = pb[1]; rb[2] = pb[2]; rb[3] = pb[3]; }
    *(short8*)((char*)ls[0] + wbyA)  = cvt8(ra[0], ra[1]);
    *(short8*)((char*)ls[0] + wbyB0) = cvt8(rb[0], rb[1]);
    *(short8*)((char*)ls[0] + wbyB1) = cvt8(rb[2], rb[3]);
    { const float4* pa = (const float4*)(gA + 32); ra[0] = pa[0]; ra[1] = pa[1];
      const float4* pb = (const float4*)(gB + 32); rb[0] = pb[0]; rb[1] = pb[1]; rb[2] = pb[2]; rb[3] = pb[3]; }
    asm volatile("s_waitcnt lgkmcnt(0)" ::: "memory");
    __builtin_amdgcn_s_barrier();

#pragma unroll
    for (int sp = 0; sp < NSTEPS; sp += 2) {
        GRAM_STEP(sp)
        GRAM_STEP(sp + 1)
    }

    const bool straddle = ((ti >> 1) == tjc);
    if (STORE) {
        __half* __restrict__ dst = (__half*)outv + (size_t)blockIdx.x * 32768;
#pragma unroll
        for (int mi = 0; mi < 4; ++mi)
#pragma unroll
            for (int ni = 0; ni < 4; ++ni)
#pragma unroll
                for (int r = 0; r < 4; ++r) {
                    int li = wr * 64 + mi * 16 + (lane >> 4) * 4 + r;
                    int lj = wc * 64 + ni * 16 + (lane & 15);
                    dst[li * 256 + lj] = __float2half_rn(acc[mi][ni][r]);
                    // norms from straddle-tile diagonals (fp32, memset-zeroed)
                    if (straddle && lj == (((ti & 1) << 7) + li))
                        atomicAdd(&norms[m * 1024 + ti * 128 + li], acc[mi][ni][r]);
                }
    } else {
        float* __restrict__ g = (float*)outv + (size_t)m * (1024 * 1024);
#pragma unroll
        for (int mi = 0; mi < 4; ++mi)
#pragma unroll
            for (int ni = 0; ni < 4; ++ni)
#pragma unroll
                for (int r = 0; r < 4; ++r) {
                    int gi = ti * 128 + wr * 64 + mi * 16 + (lane >> 4) * 4 + r;
                    int gj = tjc * 256 + wc * 64 + ni * 16 + (lane & 15);
                    if (gj >= gi) atomicAdd(&g[gi * 1024 + gj], acc[mi][ni][r]);
                }
    }
}

// loss: wave = 64 consecutive j of one i (coalesced fp16 gathers), uniform
// 16-chunk gather path; per-block partial store; tiny finalize kernel.
__global__ __launch_bounds__(256)
void loss_store_kernel(const __half* __restrict__ part, const float* __restrict__ norms,
                       float* __restrict__ partial) {
    const int tid = threadIdx.x;
    const int base = blockIdx.x * 256 + tid;
    float local = 0.f;
#pragma unroll
    for (int s = 0; s < 4; ++s) {
        int lin = base + s * 262144;
        int i = lin >> 10, j = lin & 1023;
        if (j > i) {
            int ti = i >> 7, tjc = j >> 8;
            int t = tjc * (tjc + 1) + ti;
            int el = ((i & 127) << 8) + (j & 255);
            float gp = 0.f, gt = 0.f;
#pragma unroll
            for (int c = 0; c < 16; ++c) {
                gp += __half2float(part[(size_t)bid_from(0, t, c) * 32768 + el]);
                gt += __half2float(part[(size_t)bid_from(1, t, c) * 32768 + el]);
            }
            float dp = norms[i] + norms[j] - 2.f * gp;
            float dt_ = norms[1024 + i] + norms[1024 + j] - 2.f * gt;
            float c2 = sqrtf(fmaxf(dp, 0.f)) - sqrtf(fmaxf(dt_, 0.f));
            local += c2 * c2;
        }
    }
#pragma unroll
    for (int off = 32; off > 0; off >>= 1) local += __shfl_down(local, off);
    __shared__ float wsum[4];
    if ((tid & 63) == 0) wsum[tid >> 6] = local;
    __syncthreads();
    if (tid == 0) partial[blockIdx.x] = wsum[0] + wsum[1] + wsum[2] + wsum[3];
}

// fallback loss (atomic gram path): reads dense gram[2][1024][1024], upper+diag valid
__global__ __launch_bounds__(256)
void loss_atomic_kernel(const float* __restrict__ gram, float* __restrict__ partial) {
    const float* __restrict__ gP = gram;
    const float* __restrict__ gT = gram + 1024 * 1024;
    const int tid = threadIdx.x;
    const int base = blockIdx.x * 256 + tid;
    float local = 0.f;
#pragma unroll
    for (int s = 0; s < 4; ++s) {
        int lin = base + s * 262144;
        int i = lin >> 10, j = lin & 1023;
        if (j > i) {
            float dp = gP[i * 1024 + i] + gP[j * 1024 + j] - 2.f * gP[lin];
            float dt = gT[i * 1024 + i] + gT[j * 1024 + j] - 2.f * gT[lin];
            float c = sqrtf(fmaxf(dp, 0.f)) - sqrtf(fmaxf(dt, 0.f));
            local += c * c;
        }
    }
#pragma unroll
    for (int off = 32; off > 0; off >>= 1) local += __shfl_down(local, off);
    __shared__ float wsum[4];
    if ((tid & 63) == 0) wsum[tid >> 6] = local;
    __syncthreads();
    if (tid == 0) partial[blockIdx.x] = wsum[0] + wsum[1] + wsum[2] + wsum[3];
}

__global__ __launch_bounds__(256)
void finalize_kernel(const float* __restrict__ partial, float* __restrict__ out) {
    const int tid = threadIdx.x;
    double local = 0.0;
#pragma unroll
    for (int k = 0; k < 4; ++k) local += (double)partial[tid + k * 256];
#pragma unroll
    for (int off = 32; off > 0; off >>= 1) local += __shfl_down(local, off);
    __shared__ double wsum[4];
    if ((tid & 63) == 0) wsum[tid >> 6] = local;
    __syncthreads();
    if (tid == 0) out[0] = (float)((wsum[0] + wsum[1] + wsum[2] + wsum[3]) / NPAIR);
}

extern "C" void kernel_launch(void* const* d_in, const int* in_sizes, int n_in,
                              void* d_out, int out_size, void* d_ws, size_t ws_size,
                              hipStream_t stream) {
    const float* pred = (const float*)d_in[0];
    const float* tgt  = (const float*)d_in[1];
    // layout: part fp16 [640*32768] (41.9 MB) | norms f32 [2048] | partial f32 [1024]
    const size_t part_halves = (size_t)640 * 32768;
    const size_t need = part_halves * sizeof(__half) + (2048 + 1024) * sizeof(float);
    if (ws_size >= need) {
        __half* part   = (__half*)d_ws;
        float* norms   = (float*)((char*)d_ws + part_halves * sizeof(__half));
        float* partial = norms + 2048;
        hipMemsetAsync(norms, 0, 2048 * sizeof(float), stream);
        gram_kernel<true><<<640, 512, 0, stream>>>(pred, tgt, (void*)part, norms);
        loss_store_kernel<<<1024, 256, 0, stream>>>(part, norms, partial);
        finalize_kernel<<<1, 256, 0, stream>>>(partial, (float*)d_out);
    } else {
        float* gram    = (float*)d_ws;                  // 2 x 1024 x 1024 f32 = 8 MB
        float* partial = (float*)d_ws + (size_t)2 * 1024 * 1024;
        hipMemsetAsync(gram, 0, (size_t)2 * 1024 * 1024 * sizeof(float), stream);
        gram_kernel<false><<<640, 512, 0, stream>>>(pred, tgt, (void*)gram, nullptr);
        loss_atomic_kernel<<<1024, 256, 0, stream>>>(gram, partial);
        finalize_kernel<<<1, 256, 0, stream>>>(partial, (float*)d_out);
    }
}

// Round 11
// 53.994 us; speedup vs baseline: 1.2330x; 1.2330x over previous
//
#include <hip/hip_runtime.h>
#include <hip/hip_bf16.h>
#include <hip/hip_fp16.h>

#define D 8192
#define NPAIR 523776.0

typedef short short8 __attribute__((ext_vector_type(8)));
typedef float f32x4 __attribute__((ext_vector_type(4)));
typedef _Float16 f16x8 __attribute__((ext_vector_type(8)));

__device__ __forceinline__ short8 cvt8(const float4 a, const float4 b) {
    union { short8 s; __hip_bfloat162 h[4]; } u;
    u.h[0] = __float22bfloat162_rn(make_float2(a.x, a.y));
    u.h[1] = __float22bfloat162_rn(make_float2(a.z, a.w));
    u.h[2] = __float22bfloat162_rn(make_float2(b.x, b.y));
    u.h[3] = __float22bfloat162_rn(make_float2(b.z, b.w));
    return u.s;
}

// 1024 blocks, bid = x(0..7, XCD slot) + 8*s.  m = x>>2, xr = x&3.
// DIAG FIRST (2x steps -> start at t=0 to kill the tail):
//   s < 16 : diag tiles. dt = s&7, c = (s>>3)*4 + xr (8 chunks of K=1024, 32 steps @ BK=32)
//   s >= 16: off-diag.  sp = s-16: c = (sp/28)*4 + xr (16 chunks of K=512, 16 steps @ BK=32)
__device__ __forceinline__ void decode_bid(int bid, int& m, int& ti, int& tj, int& k0, int& nsteps) {
    int x = bid & 7, s = bid >> 3;
    m = x >> 2;
    int xr = x & 3;
    if (s < 16) {
        ti = tj = s & 7;
        int c = ((s >> 3) << 2) + xr;
        k0 = c * 1024; nsteps = 32;
    } else {
        int sp = s - 16;
        int c = (sp / 28) * 4 + xr;
        int tt = sp % 28;
        int a = 0;
        while (tt >= 7 - a) { tt -= 7 - a; ++a; }
        ti = a; tj = a + 1 + tt;
        k0 = c * 512; nsteps = 16;
    }
}
__device__ __forceinline__ int bid_off(int m, int tt, int c) {
    return (m * 4 + (c & 3)) + ((16 + (c >> 2) * 28 + tt) << 3);
}
__device__ __forceinline__ int bid_diag(int m, int dt, int c) {
    return (m * 4 + (c & 3)) + ((((c >> 2) << 3) + dt) << 3);
}

// one pipeline step: MFMA on lsX[S&1]; write staged regs (data for step S+1) to
// lsX[(S&1)^1]; issue loads for step S+3 into the same (now free) register set.
#define GRAM_STEP(S, RA, RB) { \
    const int cur_ = (S) & 1; \
    const short* __restrict__ bufA = lsA[cur_]; \
    const short* __restrict__ bufB = same ? lsA[cur_] : lsB[cur_]; \
    __builtin_amdgcn_s_setprio(1); \
    short8 bf0 = *(const short8*)((const char*)bufB + (rbB + kby)); \
    short8 bf1 = *(const short8*)((const char*)bufB + (rbB + 1024 + kby)); \
    _Pragma("unroll") \
    for (int mi = 0; mi < 4; ++mi) { \
        short8 af = *(const short8*)((const char*)bufA + (rbA + mi * 1024 + kby)); \
        acc[mi][0] = __builtin_amdgcn_mfma_f32_16x16x32_bf16(af, bf0, acc[mi][0], 0, 0, 0); \
        acc[mi][1] = __builtin_amdgcn_mfma_f32_16x16x32_bf16(af, bf1, acc[mi][1], 0, 0, 0); \
    } \
    __builtin_amdgcn_s_setprio(0); \
    if ((S) + 1 < nsteps) { \
        const int nxt_ = cur_ ^ 1; \
        *(short8*)((char*)lsA[nxt_] + wby) = cvt8(RA[0], RA[1]); \
        if (!same) *(short8*)((char*)lsB[nxt_] + wby) = cvt8(RB[0], RB[1]); \
        if ((S) + 3 < nsteps) { \
            const float4* p_ = (const float4*)(gA + ((S) + 3) * 32); \
            RA[0] = p_[0]; RA[1] = p_[1]; \
            if (!same) { \
                const float4* q_ = (const float4*)(gB + ((S) + 3) * 32); \
                RB[0] = q_[0]; RB[1] = q_[1]; \
            } \
        } \
    } \
    asm volatile("s_waitcnt lgkmcnt(0)" ::: "memory"); \
    __builtin_amdgcn_s_barrier(); \
}

template<bool STORE>
__global__ __launch_bounds__(512, 4)
void gram_kernel(const float* __restrict__ pred, const float* __restrict__ tgt,
                 void* __restrict__ outv, float* __restrict__ norms) {
    int m, ti, tj, k0, nsteps;
    decode_bid(blockIdx.x, m, ti, tj, k0, nsteps);
    const bool same = (ti == tj);
    const float* __restrict__ x = m ? tgt : pred;

    __shared__ short lsA[2][4096];   // [128 rows][32 k] bf16, XOR-swizzled 16B slots
    __shared__ short lsB[2][4096];

    const int tid = threadIdx.x;
    const int lane = tid & 63;
    const int wid = tid >> 6;
    const int wr = wid >> 2, wc = wid & 3;   // 8 waves: 2x4 grid of 64x32 wave tiles

    // staging: one 8-float slot per thread per matrix: row = tid>>2, k-slot = tid&3
    const int srow = tid >> 2, sc8 = tid & 3;
    const float* __restrict__ gA = x + (size_t)(ti * 128 + srow) * D + k0 + sc8 * 8;
    const float* __restrict__ gB = x + (size_t)(tj * 128 + srow) * D + k0 + sc8 * 8;
    const int wby = srow * 64 + ((sc8 ^ ((srow >> 1) & 3)) << 4);  // swizzled LDS byte offset

    // fragment read offsets (swizzle-consistent: 16/64-row strides don't touch (row>>1)&3)
    const int rbA = (wr * 64 + (lane & 15)) * 64;
    const int rbB = (wc * 32 + (lane & 15)) * 64;
    const int kby = (((lane >> 4) ^ (((lane & 15) >> 1) & 3)) << 4);

    f32x4 zero = {0.f, 0.f, 0.f, 0.f};
    f32x4 acc[4][2];
#pragma unroll
    for (int mi = 0; mi < 4; ++mi) { acc[mi][0] = zero; acc[mi][1] = zero; }

    // two named prefetch register sets (static indexing only — no runtime-indexed arrays)
    float4 raX[2], rbX[2], raY[2], rbY[2];

    // prologue: step0 -> raX -> buf0; step1 -> raX; step2 -> raY   (depth-3 pipeline)
    { const float4* p = (const float4*)gA; raX[0] = p[0]; raX[1] = p[1];
      if (!same) { const float4* q = (const float4*)gB; rbX[0] = q[0]; rbX[1] = q[1]; } }
    *(short8*)((char*)lsA[0] + wby) = cvt8(raX[0], raX[1]);
    if (!same) *(short8*)((char*)lsB[0] + wby) = cvt8(rbX[0], rbX[1]);
    { const float4* p = (const float4*)(gA + 32); raX[0] = p[0]; raX[1] = p[1];
      if (!same) { const float4* q = (const float4*)(gB + 32); rbX[0] = q[0]; rbX[1] = q[1]; } }
    { const float4* p = (const float4*)(gA + 64); raY[0] = p[0]; raY[1] = p[1];
      if (!same) { const float4* q = (const float4*)(gB + 64); rbY[0] = q[0]; rbY[1] = q[1]; } }
    asm volatile("s_waitcnt lgkmcnt(0)" ::: "memory");
    __builtin_amdgcn_s_barrier();

    // nsteps is even (16 or 32): unrolled x2 so the set parity is compile-time static
    for (int sp = 0; sp < nsteps; sp += 2) {
        GRAM_STEP(sp,     raX, rbX)
        GRAM_STEP(sp + 1, raY, rbY)
    }

    if (STORE) {
        // fp16 partials: halves the partial write (gram) + re-read (loss) HBM traffic.
        __half* __restrict__ dst = (__half*)outv + (size_t)blockIdx.x * 16384;
#pragma unroll
        for (int mi = 0; mi < 4; ++mi)
#pragma unroll
            for (int ni = 0; ni < 2; ++ni)
#pragma unroll
                for (int r = 0; r < 4; ++r) {
                    int li = wr * 64 + mi * 16 + (lane >> 4) * 4 + r;
                    int lj = wc * 32 + ni * 16 + (lane & 15);
                    dst[li * 128 + lj] = __float2half_rn(acc[mi][ni][r]);
                    // norms from diag-tile diagonals (fp32; buffer zeroed by memsetAsync)
                    if (same && li == lj)
                        atomicAdd(&norms[m * 1024 + ti * 128 + li], acc[mi][ni][r]);
                }
    } else {
        float* __restrict__ g = (float*)outv + (size_t)m * (1024 * 1024);
#pragma unroll
        for (int mi = 0; mi < 4; ++mi)
#pragma unroll
            for (int ni = 0; ni < 2; ++ni)
#pragma unroll
                for (int r = 0; r < 4; ++r) {
                    int gi = ti * 128 + wr * 64 + mi * 16 + (lane >> 4) * 4 + r;
                    int gj = tj * 128 + wc * 32 + ni * 16 + (lane & 15);
                    atomicAdd(&g[gi * 1024 + gj], acc[mi][ni][r]);
                }
    }
}

// loss: one strip of 8 consecutive j per thread; per chunk ONE fp16x8 (16B) load
// per matrix (vs 8 scalar) -> 8x fewer gather instructions. 512 blocks x 256 thr
// = 131072 strips. Below-diagonal strips early-out.
__global__ __launch_bounds__(256)
void loss_store_kernel(const __half* __restrict__ part, const float* __restrict__ norms,
                       float* __restrict__ partial) {
    const int tid = threadIdx.x;
    const int sid = blockIdx.x * 256 + tid;      // strip id 0..131071
    const int i  = sid >> 7;                     // 0..1023
    const int j0 = (sid & 127) << 3;             // 0,8,...,1016
    float local = 0.f;
    if (j0 + 7 > i) {
        const int ti = i >> 7, tj = j0 >> 7;
        const int el = ((i & 127) << 7) + (j0 & 127);
        float gp[8] = {0,0,0,0,0,0,0,0}, gt[8] = {0,0,0,0,0,0,0,0};
        if (ti == tj) {
#pragma unroll
            for (int c = 0; c < 8; ++c) {
                f16x8 vp = *(const f16x8*)(part + (size_t)bid_diag(0, ti, c) * 16384 + el);
                f16x8 vt = *(const f16x8*)(part + (size_t)bid_diag(1, ti, c) * 16384 + el);
#pragma unroll
                for (int e = 0; e < 8; ++e) { gp[e] += (float)vp[e]; gt[e] += (float)vt[e]; }
            }
        } else {
            int tt = 7 * ti - (ti * (ti - 1)) / 2 + (tj - ti - 1);
#pragma unroll
            for (int c = 0; c < 16; ++c) {
                f16x8 vp = *(const f16x8*)(part + (size_t)bid_off(0, tt, c) * 16384 + el);
                f16x8 vt = *(const f16x8*)(part + (size_t)bid_off(1, tt, c) * 16384 + el);
#pragma unroll
                for (int e = 0; e < 8; ++e) { gp[e] += (float)vp[e]; gt[e] += (float)vt[e]; }
            }
        }
        const float nip = norms[i], nit = norms[1024 + i];
        const float4 njp0 = *(const float4*)(norms + j0);
        const float4 njp1 = *(const float4*)(norms + j0 + 4);
        const float4 njt0 = *(const float4*)(norms + 1024 + j0);
        const float4 njt1 = *(const float4*)(norms + 1024 + j0 + 4);
        const float njp[8] = {njp0.x, njp0.y, njp0.z, njp0.w, njp1.x, njp1.y, njp1.z, njp1.w};
        const float njt[8] = {njt0.x, njt0.y, njt0.z, njt0.w, njt1.x, njt1.y, njt1.z, njt1.w};
#pragma unroll
        for (int e = 0; e < 8; ++e) {
            int j = j0 + e;
            if (j > i) {
                float dp = nip + njp[e] - 2.f * gp[e];
                float dt = nit + njt[e] - 2.f * gt[e];
                float c2 = sqrtf(fmaxf(dp, 0.f)) - sqrtf(fmaxf(dt, 0.f));
                local += c2 * c2;
            }
        }
    }
#pragma unroll
    for (int off = 32; off > 0; off >>= 1) local += __shfl_down(local, off);
    __shared__ float wsum[4];
    if ((tid & 63) == 0) wsum[tid >> 6] = local;
    __syncthreads();
    if (tid == 0) partial[blockIdx.x] = wsum[0] + wsum[1] + wsum[2] + wsum[3];
}

// fallback loss (atomic gram path): reads dense gram[2][1024][1024]
__global__ __launch_bounds__(256)
void loss_atomic_kernel(const float* __restrict__ gram, float* __restrict__ partial) {
    const float* __restrict__ gP = gram;
    const float* __restrict__ gT = gram + 1024 * 1024;
    const int tid = threadIdx.x;
    const int base = blockIdx.x * 256 + tid;
    float local = 0.f;
#pragma unroll
    for (int s = 0; s < 4; ++s) {
        int lin = base + s * 262144;
        int i = lin >> 10, j = lin & 1023;
        if (j > i) {
            float dp = gP[i * 1024 + i] + gP[j * 1024 + j] - 2.f * gP[lin];
            float dt = gT[i * 1024 + i] + gT[j * 1024 + j] - 2.f * gT[lin];
            float c = sqrtf(fmaxf(dp, 0.f)) - sqrtf(fmaxf(dt, 0.f));
            local += c * c;
        }
    }
#pragma unroll
    for (int off = 32; off > 0; off >>= 1) local += __shfl_down(local, off);
    __shared__ float wsum[4];
    if ((tid & 63) == 0) wsum[tid >> 6] = local;
    __syncthreads();
    if (tid == 0) partial[blockIdx.x] = wsum[0] + wsum[1] + wsum[2] + wsum[3];
}

template<int NPART>
__global__ __launch_bounds__(256)
void finalize_kernel(const float* __restrict__ partial, float* __restrict__ out) {
    const int tid = threadIdx.x;
    double local = 0.0;
#pragma unroll
    for (int k = 0; k < NPART / 256; ++k) local += (double)partial[tid + k * 256];
#pragma unroll
    for (int off = 32; off > 0; off >>= 1) local += __shfl_down(local, off);
    __shared__ double wsum[4];
    if ((tid & 63) == 0) wsum[tid >> 6] = local;
    __syncthreads();
    if (tid == 0) out[0] = (float)((wsum[0] + wsum[1] + wsum[2] + wsum[3]) / NPAIR);
}

extern "C" void kernel_launch(void* const* d_in, const int* in_sizes, int n_in,
                              void* d_out, int out_size, void* d_ws, size_t ws_size,
                              hipStream_t stream) {
    const float* pred = (const float*)d_in[0];
    const float* tgt  = (const float*)d_in[1];
    // layout: part fp16 [1024*16384] (33.5 MB) | norms f32 [2048] | partial f32 [1024]
    const size_t part_bytes = (size_t)1024 * 16384 * sizeof(__half);
    const size_t need = part_bytes + (2048 + 1024) * sizeof(float);
    if (ws_size >= need) {
        __half* part   = (__half*)d_ws;
        float* norms   = (float*)((char*)d_ws + part_bytes);
        float* partial = norms + 2048;
        hipMemsetAsync(norms, 0, 2048 * sizeof(float), stream);
        gram_kernel<true><<<1024, 512, 0, stream>>>(pred, tgt, (void*)part, norms);
        loss_store_kernel<<<512, 256, 0, stream>>>(part, norms, partial);
        finalize_kernel<512><<<1, 256, 0, stream>>>(partial, (float*)d_out);
    } else {
        float* gram    = (float*)d_ws;                  // 2 x 1024 x 1024 f32 = 8 MB
        float* partial = (float*)d_ws + (size_t)2 * 1024 * 1024;
        hipMemsetAsync(gram, 0, (size_t)2 * 1024 * 1024 * sizeof(float), stream);
        gram_kernel<false><<<1024, 512, 0, stream>>>(pred, tgt, (void*)gram, nullptr);
        loss_atomic_kernel<<<1024, 256, 0, stream>>>(gram, partial);
        finalize_kernel<1024><<<1, 256, 0, stream>>>(partial, (float*)d_out);
    }
}